// Round 20
// baseline (294.312 us; speedup 1.0000x reference)
//
#include <hip/hip_runtime.h>
#include <hip/hip_fp16.h>

// GraphSAGE_GAT: SAGE(mean)x2 -> GAT(2 heads, softmax) -> edge MLP
// N=100000, E=1600000, D=32, H=2, EF=16.
// R20: edge_mlp_v8 = 2 adjacent edges per thread, sequential bodies
//      (e1's loads pipeline under e0's 544-FMA block; eattr reads stay
//      contiguous 128B/lane; src/dst via one int2). Everything else =
//      R19 (best 251us): 4-lane sage/gat, s_load weights, radix CSR
//      with LDS-staged radixC.

#define DD 32
#define HH 2
#define EFF 16

#define EB 4096      // edges per radix block
#define PB_T 512     // threads in radix A/B
#define BIN_SHIFT 8  // dst>>8 -> coarse bin (256 nodes/bin)
#define SEG_LDS 5120 // staged pairs per bin (mean 4096, +16 sigma)

__device__ __forceinline__ float lrelu(float x) { return x > 0.f ? x : 0.2f * x; }

// ---- generic scan phase 1: per-1024-chunk exclusive scan + chunk totals ----
__global__ void scan1_k(const int* __restrict__ in, int* __restrict__ out,
                        int* __restrict__ blockSums, int M) {
    __shared__ int s_s[256];
    int blk = blockIdx.x, t = threadIdx.x;
    int base = blk * 1024 + t * 4;
    int v[4];
    int s = 0;
#pragma unroll
    for (int i = 0; i < 4; i++) {
        v[i] = (base + i < M) ? in[base + i] : 0;
        s += v[i];
    }
    s_s[t] = s;
    __syncthreads();
    for (int off = 1; off < 256; off <<= 1) {
        int x = (t >= off) ? s_s[t - off] : 0;
        __syncthreads();
        s_s[t] += x;
        __syncthreads();
    }
    int excl = s_s[t] - s;
#pragma unroll
    for (int i = 0; i < 4; i++) {
        if (base + i < M) out[base + i] = excl;
        excl += v[i];
    }
    if (t == 255) blockSums[blk] = s_s[255];
}

// ---- generic scan phase 2: scan the chunk totals (<=256 chunks) ----
__global__ void scan2_k(int* __restrict__ blockSums, int* __restrict__ totalOut, int NB) {
    __shared__ int s_s[256];
    int t = threadIdx.x;
    int v = (t < NB) ? blockSums[t] : 0;
    s_s[t] = v;
    __syncthreads();
    for (int off = 1; off < 256; off <<= 1) {
        int x = (t >= off) ? s_s[t - off] : 0;
        __syncthreads();
        s_s[t] += x;
        __syncthreads();
    }
    if (t < NB) blockSums[t] = s_s[t] - v;  // exclusive
    if (t == 255) *totalOut = s_s[255];
}

// ---- generic scan phase 3: add chunk offsets ----
__global__ void scan3_k(int* __restrict__ out, const int* __restrict__ blockSums, int M) {
    int i = blockIdx.x * blockDim.x + threadIdx.x;
    if (i < M) out[i] += blockSums[i >> 10];
}

// ---- radix A: per-block coarse histogram (bin = dst>>8), LDS only ----
__global__ void radixA_k(const int* __restrict__ dst, int* __restrict__ histA, int E,
                         int NBLK, int NBINS) {
    __shared__ int s_h[512];
    int blk = blockIdx.x, t = threadIdx.x;
    for (int b = t; b < 512; b += PB_T) s_h[b] = 0;
    __syncthreads();
    int e0 = blk * EB;
    for (int i = t; i < EB; i += PB_T) {
        int e = e0 + i;
        if (e < E) atomicAdd(&s_h[dst[e] >> BIN_SHIFT], 1);
    }
    __syncthreads();
    for (int b = t; b < NBINS; b += PB_T) histA[b * NBLK + blk] = s_h[b];
}

// ---- radix B: place packed (src<<8)|dloc into block's private window ----
__global__ void radixB_k(const int* __restrict__ src, const int* __restrict__ dst,
                         const int* __restrict__ histScan, int* __restrict__ pairs,
                         int E, int NBLK, int NBINS) {
    __shared__ int s_base[512];
    int blk = blockIdx.x, t = threadIdx.x;
    for (int b = t; b < NBINS; b += PB_T) s_base[b] = histScan[b * NBLK + blk];
    __syncthreads();
    int e0 = blk * EB;
    for (int i = t; i < EB; i += PB_T) {
        int e = e0 + i;
        if (e < E) {
            int d = dst[e];
            int pos = atomicAdd(&s_base[d >> BIN_SHIFT], 1);  // LDS atomic only
            pairs[pos] = (src[e] << 8) | (d & 255);
        }
    }
}

// ---- radix C v3: one block per bin; pair segment staged in LDS. Builds
// rowptr for its 256 nodes and scatters soff in the bin's window. ----
__global__ void radixC_v3(const int* __restrict__ histScan, const int* __restrict__ pairs,
                          int* __restrict__ rowptr, int* __restrict__ soff, int N,
                          int NBLK, int NBINS, int E) {
    __shared__ int cnt[256];
    __shared__ int scanBuf[256];
    __shared__ int basePos[256];
    __shared__ int s_p[SEG_LDS];
    int b = blockIdx.x, t = threadIdx.x;
    int base = b << BIN_SHIFT;
    cnt[t] = 0;
    int segLo = histScan[b * NBLK];
    int segHi = (b + 1 < NBINS) ? histScan[(b + 1) * NBLK] : E;
    int len = segHi - segLo;
    int lim = min(len, SEG_LDS);
    for (int i = t; i < lim; i += 256) s_p[i] = pairs[segLo + i];
    __syncthreads();
    for (int i = t; i < len; i += 256) {
        int en = (i < SEG_LDS) ? s_p[i] : pairs[segLo + i];
        atomicAdd(&cnt[en & 255], 1);
    }
    __syncthreads();
    int v = cnt[t];
    scanBuf[t] = v;
    __syncthreads();
    for (int off = 1; off < 256; off <<= 1) {
        int x = (t >= off) ? scanBuf[t - off] : 0;
        __syncthreads();
        scanBuf[t] += x;
        __syncthreads();
    }
    int excl = segLo + scanBuf[t] - v;  // exclusive scan + segment base
    basePos[t] = excl;
    if (base + t < N) rowptr[base + t] = excl;
    if (b == NBINS - 1 && t == 0) rowptr[N] = E;
    __syncthreads();
    for (int i = t; i < len; i += 256) {
        int en = (i < SEG_LDS) ? s_p[i] : pairs[segLo + i];
        int pos = atomicAdd(&basePos[en & 255], 1);  // LDS atomic only
        soff[pos] = (en >> 8) << 6;                  // src*64
    }
}

// ---- convert fp32 -> fp16 ----
__global__ void cvt_k(const float* __restrict__ in, __half* __restrict__ out, int n) {
    int i = blockIdx.x * blockDim.x + threadIdx.x;
    if (i < n) out[i] = __float2half(in[i]);
}

// ---- c_s/c_d precompute: c4[i] = (W att_src)[i,h], (W att_dst)[i,h] ----
__global__ void prep_c_k(const float* __restrict__ w, const float* __restrict__ att_src,
                         const float* __restrict__ att_dst, float4* __restrict__ c4) {
    int i = threadIdx.x;
    if (i >= DD) return;
    float cs0 = 0.f, cs1 = 0.f, cd0 = 0.f, cd1 = 0.f;
    for (int d = 0; d < DD; d++) {
        float w0 = w[i * (HH * DD) + d], w1 = w[i * (HH * DD) + DD + d];
        cs0 += w0 * att_src[d];
        cs1 += w1 * att_src[DD + d];
        cd0 += w0 * att_dst[d];
        cd1 += w1 * att_dst[DD + d];
    }
    c4[i] = make_float4(cs0, cs1, cd0, cd1);
}

__device__ __forceinline__ void unpack8(uint4 u, float f[8]) {
    float2 a = __half22float2(*reinterpret_cast<const __half2*>(&u.x));
    float2 b = __half22float2(*reinterpret_cast<const __half2*>(&u.y));
    float2 c = __half22float2(*reinterpret_cast<const __half2*>(&u.z));
    float2 d = __half22float2(*reinterpret_cast<const __half2*>(&u.w));
    f[0] = a.x; f[1] = a.y; f[2] = b.x; f[3] = b.y;
    f[4] = c.x; f[5] = c.y; f[6] = d.x; f[7] = d.y;
}

// ---- SAGE fused v4: 4 lanes/node (features 8l..8l+7 as uint4).
// Gather-mean + lin_l + lin_r + relu -> fp16. Layer 2 (a_s!=null) also
// emits GAT scores from the in-register output. ----
__global__ void sage4x16_k(const __half* __restrict__ x, const int* __restrict__ rowptr,
                           const int* __restrict__ soff, const float* __restrict__ wl,
                           const float* __restrict__ bl, const float* __restrict__ wr,
                           __half* __restrict__ out, const float4* __restrict__ c4,
                           float2* __restrict__ a_s, float2* __restrict__ a_d, int N) {
    __shared__ float s_wl[DD * DD];
    __shared__ float s_wr[DD * DD];
    __shared__ float s_b[DD];
    __shared__ float4 s_c[DD];
    for (int i = threadIdx.x; i < DD * DD; i += blockDim.x) {
        s_wl[i] = wl[i];
        s_wr[i] = wr[i];
    }
    if (threadIdx.x < DD) {
        s_b[threadIdx.x] = bl[threadIdx.x];
        if (a_s) s_c[threadIdx.x] = c4[threadIdx.x];
    }
    __syncthreads();
    int gid = blockIdx.x * blockDim.x + threadIdx.x;
    int n = gid >> 2;
    if (n >= N) return;
    int l = gid & 3;
    int lo = rowptr[n], hi = rowptr[n + 1];
    const char* xb = (const char*)x;
    float acc[8] = {};
    int j = lo;
    for (; j + 1 < hi; j += 2) {
        int o0 = soff[j], o1 = soff[j + 1];
        uint4 r0 = *(const uint4*)(xb + o0 + l * 16);
        uint4 r1 = *(const uint4*)(xb + o1 + l * 16);
        float v0[8], v1[8];
        unpack8(r0, v0);
        unpack8(r1, v1);
#pragma unroll
        for (int f = 0; f < 8; f++) acc[f] += v0[f] + v1[f];
    }
    if (j < hi) {
        uint4 r0 = *(const uint4*)(xb + soff[j] + l * 16);
        float v0[8];
        unpack8(r0, v0);
#pragma unroll
        for (int f = 0; f < 8; f++) acc[f] += v0[f];
    }
    float inv = 1.0f / fmaxf((float)(hi - lo), 1.0f);
    float mx[8];
#pragma unroll
    for (int f = 0; f < 8; f++) mx[f] = acc[f] * inv;
    uint4 sr = *(const uint4*)(xb + (size_t)n * 64 + l * 16);
    float xv[8];
    unpack8(sr, xv);
    float o[8];
#pragma unroll
    for (int f = 0; f < 8; f++) o[f] = s_b[8 * l + f];
#pragma unroll
    for (int i2 = 0; i2 < 4; i2++) {
#pragma unroll
        for (int r = 0; r < 8; r++) {
            float bm = __shfl(mx[r], i2, 4);
            float bx = __shfl(xv[r], i2, 4);
            int row = 8 * i2 + r;
            const float4 wl0 = *(const float4*)(s_wl + row * DD + 8 * l);
            const float4 wl1 = *(const float4*)(s_wl + row * DD + 8 * l + 4);
            const float4 wr0 = *(const float4*)(s_wr + row * DD + 8 * l);
            const float4 wr1 = *(const float4*)(s_wr + row * DD + 8 * l + 4);
            o[0] += bm * wl0.x + bx * wr0.x;
            o[1] += bm * wl0.y + bx * wr0.y;
            o[2] += bm * wl0.z + bx * wr0.z;
            o[3] += bm * wl0.w + bx * wr0.w;
            o[4] += bm * wl1.x + bx * wr1.x;
            o[5] += bm * wl1.y + bx * wr1.y;
            o[6] += bm * wl1.z + bx * wr1.z;
            o[7] += bm * wl1.w + bx * wr1.w;
        }
    }
#pragma unroll
    for (int f = 0; f < 8; f++) o[f] = fmaxf(o[f], 0.f);
    uint4 ow;
    *reinterpret_cast<__half2*>(&ow.x) = __floats2half2_rn(o[0], o[1]);
    *reinterpret_cast<__half2*>(&ow.y) = __floats2half2_rn(o[2], o[3]);
    *reinterpret_cast<__half2*>(&ow.z) = __floats2half2_rn(o[4], o[5]);
    *reinterpret_cast<__half2*>(&ow.w) = __floats2half2_rn(o[6], o[7]);
    *(uint4*)((char*)out + (size_t)n * 64 + l * 16) = ow;
    if (a_s) {
        float pa0 = 0.f, pa1 = 0.f, pd0 = 0.f, pd1 = 0.f;
#pragma unroll
        for (int r = 0; r < 8; r++) {
            float4 c = s_c[8 * l + r];
            pa0 += o[r] * c.x;
            pa1 += o[r] * c.y;
            pd0 += o[r] * c.z;
            pd1 += o[r] * c.w;
        }
#pragma unroll
        for (int off = 2; off > 0; off >>= 1) {
            pa0 += __shfl_xor(pa0, off, 4);
            pa1 += __shfl_xor(pa1, off, 4);
            pd0 += __shfl_xor(pd0, off, 4);
            pd1 += __shfl_xor(pd1, off, 4);
        }
        if (l == 0) {
            a_s[n] = make_float2(pa0, pa1);
            a_d[n] = make_float2(pd0, pd1);
        }
    }
}

// ---- GAT aggregate v11: 4 lanes/node, inline softmax weights, uint4 gathers
// -> W transform -> head-mean+bias+relu -> fused mlp-pre ----
__global__ void gat_agg_v11(const __half* __restrict__ x2, const float2* __restrict__ a_s,
                            const float2* __restrict__ a_d, const int* __restrict__ rowptr,
                            const int* __restrict__ soff, const float* __restrict__ gw,
                            const float* __restrict__ bias, const float* __restrict__ w1,
                            const float* __restrict__ b1, __half* __restrict__ Ps,
                            __half* __restrict__ Pd, int N) {
    __shared__ float s_gw[DD * HH * DD];  // gat W: 32 x 64
    __shared__ float s_w1[2 * DD * DD];   // mlp w1 rows 0..63
    __shared__ float s_b1[DD];
    __shared__ float s_bias[DD];
    int t = threadIdx.x;
    for (int i = t; i < DD * HH * DD; i += blockDim.x) s_gw[i] = gw[i];
    for (int i = t; i < 2 * DD * DD; i += blockDim.x) s_w1[i] = w1[i];
    if (t < DD) {
        s_b1[t] = b1[t];
        s_bias[t] = bias[t];
    }
    __syncthreads();
    int gid = blockIdx.x * blockDim.x + t;
    int n = gid >> 2;
    if (n >= N) return;
    int l = gid & 3;
    const char* xb = (const char*)x2;
    const char* asb = (const char*)a_s;
    int lo = rowptr[n], hi = rowptr[n + 1];
    float2 as = a_s[n], ad = a_d[n];
    float ws0 = __expf(lrelu(as.x + ad.x));
    float ws1 = __expf(lrelu(as.y + ad.y));
    uint4 sr = *(const uint4*)(xb + (size_t)n * 64 + l * 16);
    float xvs[8];
    unpack8(sr, xvs);
    float den0 = ws0, den1 = ws1;
    float y0[8], y1[8];
#pragma unroll
    for (int f = 0; f < 8; f++) {
        y0[f] = ws0 * xvs[f];
        y1[f] = ws1 * xvs[f];
    }
    int j = lo;
    for (; j + 1 < hi; j += 2) {
        int o0 = soff[j], o1 = soff[j + 1];
        float2 s0 = *(const float2*)(asb + (o0 >> 3));
        float2 s1 = *(const float2*)(asb + (o1 >> 3));
        uint4 r0 = *(const uint4*)(xb + o0 + l * 16);
        uint4 r1 = *(const uint4*)(xb + o1 + l * 16);
        float w00 = __expf(lrelu(s0.x + ad.x)), w01 = __expf(lrelu(s0.y + ad.y));
        float w10 = __expf(lrelu(s1.x + ad.x)), w11 = __expf(lrelu(s1.y + ad.y));
        den0 += w00 + w10;
        den1 += w01 + w11;
        float v0[8], v1[8];
        unpack8(r0, v0);
        unpack8(r1, v1);
#pragma unroll
        for (int f = 0; f < 8; f++) {
            y0[f] += w00 * v0[f] + w10 * v1[f];
            y1[f] += w01 * v0[f] + w11 * v1[f];
        }
    }
    if (j < hi) {
        int o0 = soff[j];
        float2 s0 = *(const float2*)(asb + (o0 >> 3));
        uint4 r0 = *(const uint4*)(xb + o0 + l * 16);
        float w00 = __expf(lrelu(s0.x + ad.x)), w01 = __expf(lrelu(s0.y + ad.y));
        den0 += w00;
        den1 += w01;
        float v0[8];
        unpack8(r0, v0);
#pragma unroll
        for (int f = 0; f < 8; f++) {
            y0[f] += w00 * v0[f];
            y1[f] += w01 * v0[f];
        }
    }
    float i0 = 1.0f / (den0 + 1e-16f), i1 = 1.0f / (den1 + 1e-16f);
    float u0[8], u1[8];
#pragma unroll
    for (int f = 0; f < 8; f++) {
        u0[f] = y0[f] * i0;
        u1[f] = y1[f] * i1;
    }
    // o[kk] = 0.5*(sum_i u0[i] gw[i][kk] + u1[i] gw[i][32+kk]) + bias, relu
    float o[8] = {};
#pragma unroll
    for (int i2 = 0; i2 < 4; i2++) {
#pragma unroll
        for (int r = 0; r < 8; r++) {
            float b0 = __shfl(u0[r], i2, 4);
            float b1v = __shfl(u1[r], i2, 4);
            int row = 8 * i2 + r;
            const float4 g00 = *(const float4*)(s_gw + row * (HH * DD) + 8 * l);
            const float4 g01 = *(const float4*)(s_gw + row * (HH * DD) + 8 * l + 4);
            const float4 g10 = *(const float4*)(s_gw + row * (HH * DD) + DD + 8 * l);
            const float4 g11 = *(const float4*)(s_gw + row * (HH * DD) + DD + 8 * l + 4);
            o[0] += b0 * g00.x + b1v * g10.x;
            o[1] += b0 * g00.y + b1v * g10.y;
            o[2] += b0 * g00.z + b1v * g10.z;
            o[3] += b0 * g00.w + b1v * g10.w;
            o[4] += b0 * g01.x + b1v * g11.x;
            o[5] += b0 * g01.y + b1v * g11.y;
            o[6] += b0 * g01.z + b1v * g11.z;
            o[7] += b0 * g01.w + b1v * g11.w;
        }
    }
#pragma unroll
    for (int f = 0; f < 8; f++) o[f] = fmaxf(0.5f * o[f] + s_bias[8 * l + f], 0.f);
    // fused mlp-pre: Ps (rows 0..31 of w1, +b1), Pd (rows 32..63)
    float ps[8], pd[8];
#pragma unroll
    for (int f = 0; f < 8; f++) {
        ps[f] = s_b1[8 * l + f];
        pd[f] = 0.f;
    }
#pragma unroll
    for (int i2 = 0; i2 < 4; i2++) {
#pragma unroll
        for (int r = 0; r < 8; r++) {
            float bo = __shfl(o[r], i2, 4);
            int row = 8 * i2 + r;
            const float4 wa0 = *(const float4*)(s_w1 + row * DD + 8 * l);
            const float4 wa1 = *(const float4*)(s_w1 + row * DD + 8 * l + 4);
            const float4 wb0 = *(const float4*)(s_w1 + (DD + row) * DD + 8 * l);
            const float4 wb1 = *(const float4*)(s_w1 + (DD + row) * DD + 8 * l + 4);
            ps[0] += bo * wa0.x;
            ps[1] += bo * wa0.y;
            ps[2] += bo * wa0.z;
            ps[3] += bo * wa0.w;
            ps[4] += bo * wa1.x;
            ps[5] += bo * wa1.y;
            ps[6] += bo * wa1.z;
            ps[7] += bo * wa1.w;
            pd[0] += bo * wb0.x;
            pd[1] += bo * wb0.y;
            pd[2] += bo * wb0.z;
            pd[3] += bo * wb0.w;
            pd[4] += bo * wb1.x;
            pd[5] += bo * wb1.y;
            pd[6] += bo * wb1.z;
            pd[7] += bo * wb1.w;
        }
    }
    uint4 pw;
    *reinterpret_cast<__half2*>(&pw.x) = __floats2half2_rn(ps[0], ps[1]);
    *reinterpret_cast<__half2*>(&pw.y) = __floats2half2_rn(ps[2], ps[3]);
    *reinterpret_cast<__half2*>(&pw.z) = __floats2half2_rn(ps[4], ps[5]);
    *reinterpret_cast<__half2*>(&pw.w) = __floats2half2_rn(ps[6], ps[7]);
    *(uint4*)((char*)Ps + (size_t)n * 64 + l * 16) = pw;
    *reinterpret_cast<__half2*>(&pw.x) = __floats2half2_rn(pd[0], pd[1]);
    *reinterpret_cast<__half2*>(&pw.y) = __floats2half2_rn(pd[2], pd[3]);
    *reinterpret_cast<__half2*>(&pw.z) = __floats2half2_rn(pd[4], pd[5]);
    *reinterpret_cast<__half2*>(&pw.w) = __floats2half2_rn(pd[6], pd[7]);
    *(uint4*)((char*)Pd + (size_t)n * 64 + l * 16) = pw;
}

// ---- Edge MLP v8: 2 adjacent edges per thread, sequential bodies.
// Weights via wave-uniform s_load (scalar cache). e1's loads pipeline
// under e0's 544-FMA block. ----
__device__ __forceinline__ float edge_one(const __half* __restrict__ Ps,
                                          const __half* __restrict__ Pd,
                                          const float* __restrict__ eattr,
                                          const float* __restrict__ w1e,
                                          const float* __restrict__ w2, float b2v,
                                          int s, int d, int e) {
    float acc[DD] = {};
    {
        const uint4* r4 = (const uint4*)((const char*)Ps + (size_t)s * 64);
        const uint4* q4 = (const uint4*)((const char*)Pd + (size_t)d * 64);
#pragma unroll
        for (int c = 0; c < 4; c++) {
            uint4 u = r4[c];
            uint4 w = q4[c];
            unsigned uu[4] = {u.x, u.y, u.z, u.w};
            unsigned ww[4] = {w.x, w.y, w.z, w.w};
#pragma unroll
            for (int t2 = 0; t2 < 4; t2++) {
                float2 fa = __half22float2(*reinterpret_cast<const __half2*>(&uu[t2]));
                float2 fb = __half22float2(*reinterpret_cast<const __half2*>(&ww[t2]));
                acc[c * 8 + t2 * 2 + 0] += fa.x + fb.x;
                acc[c * 8 + t2 * 2 + 1] += fa.y + fb.y;
            }
        }
    }
    const float4* ea4 = (const float4*)(eattr + (size_t)e * EFF);
#pragma unroll
    for (int c = 0; c < 4; c++) {
        float4 v = ea4[c];
        const float va[4] = {v.x, v.y, v.z, v.w};
#pragma unroll
        for (int r = 0; r < 4; r++) {
#pragma unroll
            for (int j4 = 0; j4 < 8; j4++) {
                const float4 w = *(const float4*)(w1e + (c * 4 + r) * DD + j4 * 4);
                acc[j4 * 4 + 0] += va[r] * w.x;
                acc[j4 * 4 + 1] += va[r] * w.y;
                acc[j4 * 4 + 2] += va[r] * w.z;
                acc[j4 * 4 + 3] += va[r] * w.w;
            }
        }
    }
    float p = b2v;
#pragma unroll
    for (int j = 0; j < DD; j++) p += fmaxf(acc[j], 0.f) * w2[j];
    return p;
}

__global__ void edge_mlp_v8(const __half* __restrict__ Ps, const __half* __restrict__ Pd,
                            const float* __restrict__ eattr, const int* __restrict__ src,
                            const int* __restrict__ dst, const float* __restrict__ w1e,
                            const float* __restrict__ w2, const float* __restrict__ b2,
                            float* __restrict__ out, int E) {
    int base = (blockIdx.x * blockDim.x + threadIdx.x) * 2;
    if (base >= E) return;
    float b2v = b2[0];
    int2 s2 = *(const int2*)(src + base);
    int2 d2 = *(const int2*)(dst + base);
    float p0 = edge_one(Ps, Pd, eattr, w1e, w2, b2v, s2.x, d2.x, base);
    if (base + 1 < E) {
        float p1 = edge_one(Ps, Pd, eattr, w1e, w2, b2v, s2.y, d2.y, base + 1);
        *(float2*)(out + base) = make_float2(p0, p1);
    } else {
        out[base] = p0;
    }
}

extern "C" void kernel_launch(void* const* d_in, const int* in_sizes, int n_in,
                              void* d_out, int out_size, void* d_ws, size_t ws_size,
                              hipStream_t stream) {
    const int E = in_sizes[0] / 2;
    const int N = in_sizes[2] / DD;

    const int* src = (const int*)d_in[0];
    const int* dst = src + E;
    const float* edge_attr = (const float*)d_in[1];
    const float* node_emb = (const float*)d_in[2];
    const float* sage1_wl = (const float*)d_in[3];
    const float* sage1_bl = (const float*)d_in[4];
    const float* sage1_wr = (const float*)d_in[5];
    const float* sage2_wl = (const float*)d_in[6];
    const float* sage2_bl = (const float*)d_in[7];
    const float* sage2_wr = (const float*)d_in[8];
    const float* gat_w = (const float*)d_in[9];
    const float* gat_att_src = (const float*)d_in[10];
    const float* gat_att_dst = (const float*)d_in[11];
    const float* gat_bias = (const float*)d_in[12];
    const float* mlp_w1 = (const float*)d_in[13];
    const float* mlp_b1 = (const float*)d_in[14];
    const float* mlp_w2 = (const float*)d_in[15];
    const float* mlp_b2 = (const float*)d_in[16];
    float* out = (float*)d_out;

    const int NBINS = (N + 255) >> BIN_SHIFT;
    const int NBLK = (E + EB - 1) / EB;
    const int M = NBINS * NBLK;

    // Workspace layout (256B-aligned chunks)
    char* ws = (char*)d_ws;
    size_t off = 0;
    auto alloc = [&](size_t bytes) {
        char* p = ws + off;
        off = (off + bytes + 255) & ~(size_t)255;
        return p;
    };
    int* rowptr = (int*)alloc((size_t)(N + 1) * 4);
    int* blockSums = (int*)alloc(256 * 4);
    int* dTot = (int*)alloc(4);
    int* soff = (int*)alloc((size_t)E * 4);
    __half* x0h = (__half*)alloc((size_t)N * DD * 2);
    __half* x1h = (__half*)alloc((size_t)N * DD * 2);
    __half* x2h = (__half*)alloc((size_t)N * DD * 2);
    float2* a_s = (float2*)alloc((size_t)N * 8);
    float2* a_d = (float2*)alloc((size_t)N * 8);
    float4* c4 = (float4*)alloc(DD * 16);
    __half* Ps = (__half*)alloc((size_t)N * DD * 2);
    __half* Pd = (__half*)alloc((size_t)N * DD * 2);
    int* histA = (int*)alloc((size_t)M * 4);
    int* histScan = (int*)alloc((size_t)M * 4);
    int* pairs = (int*)alloc((size_t)E * 4);

    const int BS = 256;
    const int gE2 = (E / 2 + BS - 1) / BS;
    const int gN32 = (N * 32 + BS - 1) / BS;
    const int gN4 = (N * 4 + BS - 1) / BS;
    const int NBm = (M + 1023) / 1024;

    // ---- CSR build: counting sort; rowptr built inside radixC ----
    radixA_k<<<NBLK, PB_T, 0, stream>>>(dst, histA, E, NBLK, NBINS);
    scan1_k<<<NBm, 256, 0, stream>>>(histA, histScan, blockSums, M);
    scan2_k<<<1, 256, 0, stream>>>(blockSums, dTot, NBm);
    scan3_k<<<(M + BS - 1) / BS, BS, 0, stream>>>(histScan, blockSums, M);
    radixB_k<<<NBLK, PB_T, 0, stream>>>(src, dst, histScan, pairs, E, NBLK, NBINS);
    radixC_v3<<<NBINS, 256, 0, stream>>>(histScan, pairs, rowptr, soff, N, NBLK, NBINS, E);

    // ---- fp16 input conversion + attention coefficient vectors ----
    cvt_k<<<gN32, BS, 0, stream>>>(node_emb, x0h, N * DD);
    prep_c_k<<<1, 64, 0, stream>>>(gat_w, gat_att_src, gat_att_dst, c4);

    // ---- SAGE layers (layer 2 also emits GAT scores) ----
    sage4x16_k<<<gN4, BS, 0, stream>>>(x0h, rowptr, soff, sage1_wl, sage1_bl, sage1_wr,
                                       x1h, nullptr, nullptr, nullptr, N);
    sage4x16_k<<<gN4, BS, 0, stream>>>(x1h, rowptr, soff, sage2_wl, sage2_bl, sage2_wr,
                                       x2h, c4, a_s, a_d, N);

    // ---- GAT aggregate (+ inline softmax weights + fused mlp-pre) ----
    gat_agg_v11<<<gN4, BS, 0, stream>>>(x2h, a_s, a_d, rowptr, soff, gat_w, gat_bias,
                                        mlp_w1, mlp_b1, Ps, Pd, N);

    // ---- Edge MLP (2 edges/thread; weights via scalar cache) ----
    edge_mlp_v8<<<gE2, BS, 0, stream>>>(Ps, Pd, edge_attr, src, dst,
                                        mlp_w1 + 2 * DD * DD, mlp_w2, mlp_b2, out, E);
}

// Round 21
// 250.593 us; speedup vs baseline: 1.1745x; 1.1745x over previous
//
#include <hip/hip_runtime.h>
#include <hip/hip_fp16.h>

// GraphSAGE_GAT: SAGE(mean)x2 -> GAT(2 heads, softmax) -> edge MLP
// N=100000, E=1600000, D=32, H=2, EF=16.
// R21: exact revert to the proven R19 configuration (best: 251us).
//      R20's 2-edge/thread edge_mlp regressed (FETCH 209->354MB: serialized
//      bodies + broken eattr line reuse). Final config: radix-sort CSR
//      (zero global atomics, LDS-staged radixC), fp16 feature tables,
//      4-lane/node fused SAGE (layer2 emits GAT scores), 4-lane GAT
//      aggregate with inline softmax + fused edge-MLP precompute,
//      edge MLP with s_load weights (zero LDS).

#define DD 32
#define HH 2
#define EFF 16

#define EB 4096      // edges per radix block
#define PB_T 512     // threads in radix A/B
#define BIN_SHIFT 8  // dst>>8 -> coarse bin (256 nodes/bin)
#define SEG_LDS 5120 // staged pairs per bin (mean 4096, +16 sigma)

__device__ __forceinline__ float lrelu(float x) { return x > 0.f ? x : 0.2f * x; }

// ---- generic scan phase 1: per-1024-chunk exclusive scan + chunk totals ----
__global__ void scan1_k(const int* __restrict__ in, int* __restrict__ out,
                        int* __restrict__ blockSums, int M) {
    __shared__ int s_s[256];
    int blk = blockIdx.x, t = threadIdx.x;
    int base = blk * 1024 + t * 4;
    int v[4];
    int s = 0;
#pragma unroll
    for (int i = 0; i < 4; i++) {
        v[i] = (base + i < M) ? in[base + i] : 0;
        s += v[i];
    }
    s_s[t] = s;
    __syncthreads();
    for (int off = 1; off < 256; off <<= 1) {
        int x = (t >= off) ? s_s[t - off] : 0;
        __syncthreads();
        s_s[t] += x;
        __syncthreads();
    }
    int excl = s_s[t] - s;
#pragma unroll
    for (int i = 0; i < 4; i++) {
        if (base + i < M) out[base + i] = excl;
        excl += v[i];
    }
    if (t == 255) blockSums[blk] = s_s[255];
}

// ---- generic scan phase 2: scan the chunk totals (<=256 chunks) ----
__global__ void scan2_k(int* __restrict__ blockSums, int* __restrict__ totalOut, int NB) {
    __shared__ int s_s[256];
    int t = threadIdx.x;
    int v = (t < NB) ? blockSums[t] : 0;
    s_s[t] = v;
    __syncthreads();
    for (int off = 1; off < 256; off <<= 1) {
        int x = (t >= off) ? s_s[t - off] : 0;
        __syncthreads();
        s_s[t] += x;
        __syncthreads();
    }
    if (t < NB) blockSums[t] = s_s[t] - v;  // exclusive
    if (t == 255) *totalOut = s_s[255];
}

// ---- generic scan phase 3: add chunk offsets ----
__global__ void scan3_k(int* __restrict__ out, const int* __restrict__ blockSums, int M) {
    int i = blockIdx.x * blockDim.x + threadIdx.x;
    if (i < M) out[i] += blockSums[i >> 10];
}

// ---- radix A: per-block coarse histogram (bin = dst>>8), LDS only ----
__global__ void radixA_k(const int* __restrict__ dst, int* __restrict__ histA, int E,
                         int NBLK, int NBINS) {
    __shared__ int s_h[512];
    int blk = blockIdx.x, t = threadIdx.x;
    for (int b = t; b < 512; b += PB_T) s_h[b] = 0;
    __syncthreads();
    int e0 = blk * EB;
    for (int i = t; i < EB; i += PB_T) {
        int e = e0 + i;
        if (e < E) atomicAdd(&s_h[dst[e] >> BIN_SHIFT], 1);
    }
    __syncthreads();
    for (int b = t; b < NBINS; b += PB_T) histA[b * NBLK + blk] = s_h[b];
}

// ---- radix B: place packed (src<<8)|dloc into block's private window ----
__global__ void radixB_k(const int* __restrict__ src, const int* __restrict__ dst,
                         const int* __restrict__ histScan, int* __restrict__ pairs,
                         int E, int NBLK, int NBINS) {
    __shared__ int s_base[512];
    int blk = blockIdx.x, t = threadIdx.x;
    for (int b = t; b < NBINS; b += PB_T) s_base[b] = histScan[b * NBLK + blk];
    __syncthreads();
    int e0 = blk * EB;
    for (int i = t; i < EB; i += PB_T) {
        int e = e0 + i;
        if (e < E) {
            int d = dst[e];
            int pos = atomicAdd(&s_base[d >> BIN_SHIFT], 1);  // LDS atomic only
            pairs[pos] = (src[e] << 8) | (d & 255);
        }
    }
}

// ---- radix C v3: one block per bin; pair segment staged in LDS. Builds
// rowptr for its 256 nodes and scatters soff in the bin's window. ----
__global__ void radixC_v3(const int* __restrict__ histScan, const int* __restrict__ pairs,
                          int* __restrict__ rowptr, int* __restrict__ soff, int N,
                          int NBLK, int NBINS, int E) {
    __shared__ int cnt[256];
    __shared__ int scanBuf[256];
    __shared__ int basePos[256];
    __shared__ int s_p[SEG_LDS];
    int b = blockIdx.x, t = threadIdx.x;
    int base = b << BIN_SHIFT;
    cnt[t] = 0;
    int segLo = histScan[b * NBLK];
    int segHi = (b + 1 < NBINS) ? histScan[(b + 1) * NBLK] : E;
    int len = segHi - segLo;
    int lim = min(len, SEG_LDS);
    for (int i = t; i < lim; i += 256) s_p[i] = pairs[segLo + i];
    __syncthreads();
    for (int i = t; i < len; i += 256) {
        int en = (i < SEG_LDS) ? s_p[i] : pairs[segLo + i];
        atomicAdd(&cnt[en & 255], 1);
    }
    __syncthreads();
    int v = cnt[t];
    scanBuf[t] = v;
    __syncthreads();
    for (int off = 1; off < 256; off <<= 1) {
        int x = (t >= off) ? scanBuf[t - off] : 0;
        __syncthreads();
        scanBuf[t] += x;
        __syncthreads();
    }
    int excl = segLo + scanBuf[t] - v;  // exclusive scan + segment base
    basePos[t] = excl;
    if (base + t < N) rowptr[base + t] = excl;
    if (b == NBINS - 1 && t == 0) rowptr[N] = E;
    __syncthreads();
    for (int i = t; i < len; i += 256) {
        int en = (i < SEG_LDS) ? s_p[i] : pairs[segLo + i];
        int pos = atomicAdd(&basePos[en & 255], 1);  // LDS atomic only
        soff[pos] = (en >> 8) << 6;                  // src*64
    }
}

// ---- convert fp32 -> fp16 ----
__global__ void cvt_k(const float* __restrict__ in, __half* __restrict__ out, int n) {
    int i = blockIdx.x * blockDim.x + threadIdx.x;
    if (i < n) out[i] = __float2half(in[i]);
}

// ---- c_s/c_d precompute: c4[i] = (W att_src)[i,h], (W att_dst)[i,h] ----
__global__ void prep_c_k(const float* __restrict__ w, const float* __restrict__ att_src,
                         const float* __restrict__ att_dst, float4* __restrict__ c4) {
    int i = threadIdx.x;
    if (i >= DD) return;
    float cs0 = 0.f, cs1 = 0.f, cd0 = 0.f, cd1 = 0.f;
    for (int d = 0; d < DD; d++) {
        float w0 = w[i * (HH * DD) + d], w1 = w[i * (HH * DD) + DD + d];
        cs0 += w0 * att_src[d];
        cs1 += w1 * att_src[DD + d];
        cd0 += w0 * att_dst[d];
        cd1 += w1 * att_dst[DD + d];
    }
    c4[i] = make_float4(cs0, cs1, cd0, cd1);
}

__device__ __forceinline__ void unpack8(uint4 u, float f[8]) {
    float2 a = __half22float2(*reinterpret_cast<const __half2*>(&u.x));
    float2 b = __half22float2(*reinterpret_cast<const __half2*>(&u.y));
    float2 c = __half22float2(*reinterpret_cast<const __half2*>(&u.z));
    float2 d = __half22float2(*reinterpret_cast<const __half2*>(&u.w));
    f[0] = a.x; f[1] = a.y; f[2] = b.x; f[3] = b.y;
    f[4] = c.x; f[5] = c.y; f[6] = d.x; f[7] = d.y;
}

// ---- SAGE fused v4: 4 lanes/node (features 8l..8l+7 as uint4).
// Gather-mean + lin_l + lin_r + relu -> fp16. Layer 2 (a_s!=null) also
// emits GAT scores from the in-register output. ----
__global__ void sage4x16_k(const __half* __restrict__ x, const int* __restrict__ rowptr,
                           const int* __restrict__ soff, const float* __restrict__ wl,
                           const float* __restrict__ bl, const float* __restrict__ wr,
                           __half* __restrict__ out, const float4* __restrict__ c4,
                           float2* __restrict__ a_s, float2* __restrict__ a_d, int N) {
    __shared__ float s_wl[DD * DD];
    __shared__ float s_wr[DD * DD];
    __shared__ float s_b[DD];
    __shared__ float4 s_c[DD];
    for (int i = threadIdx.x; i < DD * DD; i += blockDim.x) {
        s_wl[i] = wl[i];
        s_wr[i] = wr[i];
    }
    if (threadIdx.x < DD) {
        s_b[threadIdx.x] = bl[threadIdx.x];
        if (a_s) s_c[threadIdx.x] = c4[threadIdx.x];
    }
    __syncthreads();
    int gid = blockIdx.x * blockDim.x + threadIdx.x;
    int n = gid >> 2;
    if (n >= N) return;
    int l = gid & 3;
    int lo = rowptr[n], hi = rowptr[n + 1];
    const char* xb = (const char*)x;
    float acc[8] = {};
    int j = lo;
    for (; j + 1 < hi; j += 2) {
        int o0 = soff[j], o1 = soff[j + 1];
        uint4 r0 = *(const uint4*)(xb + o0 + l * 16);
        uint4 r1 = *(const uint4*)(xb + o1 + l * 16);
        float v0[8], v1[8];
        unpack8(r0, v0);
        unpack8(r1, v1);
#pragma unroll
        for (int f = 0; f < 8; f++) acc[f] += v0[f] + v1[f];
    }
    if (j < hi) {
        uint4 r0 = *(const uint4*)(xb + soff[j] + l * 16);
        float v0[8];
        unpack8(r0, v0);
#pragma unroll
        for (int f = 0; f < 8; f++) acc[f] += v0[f];
    }
    float inv = 1.0f / fmaxf((float)(hi - lo), 1.0f);
    float mx[8];
#pragma unroll
    for (int f = 0; f < 8; f++) mx[f] = acc[f] * inv;
    uint4 sr = *(const uint4*)(xb + (size_t)n * 64 + l * 16);
    float xv[8];
    unpack8(sr, xv);
    float o[8];
#pragma unroll
    for (int f = 0; f < 8; f++) o[f] = s_b[8 * l + f];
#pragma unroll
    for (int i2 = 0; i2 < 4; i2++) {
#pragma unroll
        for (int r = 0; r < 8; r++) {
            float bm = __shfl(mx[r], i2, 4);
            float bx = __shfl(xv[r], i2, 4);
            int row = 8 * i2 + r;
            const float4 wl0 = *(const float4*)(s_wl + row * DD + 8 * l);
            const float4 wl1 = *(const float4*)(s_wl + row * DD + 8 * l + 4);
            const float4 wr0 = *(const float4*)(s_wr + row * DD + 8 * l);
            const float4 wr1 = *(const float4*)(s_wr + row * DD + 8 * l + 4);
            o[0] += bm * wl0.x + bx * wr0.x;
            o[1] += bm * wl0.y + bx * wr0.y;
            o[2] += bm * wl0.z + bx * wr0.z;
            o[3] += bm * wl0.w + bx * wr0.w;
            o[4] += bm * wl1.x + bx * wr1.x;
            o[5] += bm * wl1.y + bx * wr1.y;
            o[6] += bm * wl1.z + bx * wr1.z;
            o[7] += bm * wl1.w + bx * wr1.w;
        }
    }
#pragma unroll
    for (int f = 0; f < 8; f++) o[f] = fmaxf(o[f], 0.f);
    uint4 ow;
    *reinterpret_cast<__half2*>(&ow.x) = __floats2half2_rn(o[0], o[1]);
    *reinterpret_cast<__half2*>(&ow.y) = __floats2half2_rn(o[2], o[3]);
    *reinterpret_cast<__half2*>(&ow.z) = __floats2half2_rn(o[4], o[5]);
    *reinterpret_cast<__half2*>(&ow.w) = __floats2half2_rn(o[6], o[7]);
    *(uint4*)((char*)out + (size_t)n * 64 + l * 16) = ow;
    if (a_s) {
        float pa0 = 0.f, pa1 = 0.f, pd0 = 0.f, pd1 = 0.f;
#pragma unroll
        for (int r = 0; r < 8; r++) {
            float4 c = s_c[8 * l + r];
            pa0 += o[r] * c.x;
            pa1 += o[r] * c.y;
            pd0 += o[r] * c.z;
            pd1 += o[r] * c.w;
        }
#pragma unroll
        for (int off = 2; off > 0; off >>= 1) {
            pa0 += __shfl_xor(pa0, off, 4);
            pa1 += __shfl_xor(pa1, off, 4);
            pd0 += __shfl_xor(pd0, off, 4);
            pd1 += __shfl_xor(pd1, off, 4);
        }
        if (l == 0) {
            a_s[n] = make_float2(pa0, pa1);
            a_d[n] = make_float2(pd0, pd1);
        }
    }
}

// ---- GAT aggregate v11: 4 lanes/node, inline softmax weights, uint4 gathers
// -> W transform -> head-mean+bias+relu -> fused mlp-pre ----
__global__ void gat_agg_v11(const __half* __restrict__ x2, const float2* __restrict__ a_s,
                            const float2* __restrict__ a_d, const int* __restrict__ rowptr,
                            const int* __restrict__ soff, const float* __restrict__ gw,
                            const float* __restrict__ bias, const float* __restrict__ w1,
                            const float* __restrict__ b1, __half* __restrict__ Ps,
                            __half* __restrict__ Pd, int N) {
    __shared__ float s_gw[DD * HH * DD];  // gat W: 32 x 64
    __shared__ float s_w1[2 * DD * DD];   // mlp w1 rows 0..63
    __shared__ float s_b1[DD];
    __shared__ float s_bias[DD];
    int t = threadIdx.x;
    for (int i = t; i < DD * HH * DD; i += blockDim.x) s_gw[i] = gw[i];
    for (int i = t; i < 2 * DD * DD; i += blockDim.x) s_w1[i] = w1[i];
    if (t < DD) {
        s_b1[t] = b1[t];
        s_bias[t] = bias[t];
    }
    __syncthreads();
    int gid = blockIdx.x * blockDim.x + t;
    int n = gid >> 2;
    if (n >= N) return;
    int l = gid & 3;
    const char* xb = (const char*)x2;
    const char* asb = (const char*)a_s;
    int lo = rowptr[n], hi = rowptr[n + 1];
    float2 as = a_s[n], ad = a_d[n];
    float ws0 = __expf(lrelu(as.x + ad.x));
    float ws1 = __expf(lrelu(as.y + ad.y));
    uint4 sr = *(const uint4*)(xb + (size_t)n * 64 + l * 16);
    float xvs[8];
    unpack8(sr, xvs);
    float den0 = ws0, den1 = ws1;
    float y0[8], y1[8];
#pragma unroll
    for (int f = 0; f < 8; f++) {
        y0[f] = ws0 * xvs[f];
        y1[f] = ws1 * xvs[f];
    }
    int j = lo;
    for (; j + 1 < hi; j += 2) {
        int o0 = soff[j], o1 = soff[j + 1];
        float2 s0 = *(const float2*)(asb + (o0 >> 3));
        float2 s1 = *(const float2*)(asb + (o1 >> 3));
        uint4 r0 = *(const uint4*)(xb + o0 + l * 16);
        uint4 r1 = *(const uint4*)(xb + o1 + l * 16);
        float w00 = __expf(lrelu(s0.x + ad.x)), w01 = __expf(lrelu(s0.y + ad.y));
        float w10 = __expf(lrelu(s1.x + ad.x)), w11 = __expf(lrelu(s1.y + ad.y));
        den0 += w00 + w10;
        den1 += w01 + w11;
        float v0[8], v1[8];
        unpack8(r0, v0);
        unpack8(r1, v1);
#pragma unroll
        for (int f = 0; f < 8; f++) {
            y0[f] += w00 * v0[f] + w10 * v1[f];
            y1[f] += w01 * v0[f] + w11 * v1[f];
        }
    }
    if (j < hi) {
        int o0 = soff[j];
        float2 s0 = *(const float2*)(asb + (o0 >> 3));
        uint4 r0 = *(const uint4*)(xb + o0 + l * 16);
        float w00 = __expf(lrelu(s0.x + ad.x)), w01 = __expf(lrelu(s0.y + ad.y));
        den0 += w00;
        den1 += w01;
        float v0[8];
        unpack8(r0, v0);
#pragma unroll
        for (int f = 0; f < 8; f++) {
            y0[f] += w00 * v0[f];
            y1[f] += w01 * v0[f];
        }
    }
    float i0 = 1.0f / (den0 + 1e-16f), i1 = 1.0f / (den1 + 1e-16f);
    float u0[8], u1[8];
#pragma unroll
    for (int f = 0; f < 8; f++) {
        u0[f] = y0[f] * i0;
        u1[f] = y1[f] * i1;
    }
    // o[kk] = 0.5*(sum_i u0[i] gw[i][kk] + u1[i] gw[i][32+kk]) + bias, relu
    float o[8] = {};
#pragma unroll
    for (int i2 = 0; i2 < 4; i2++) {
#pragma unroll
        for (int r = 0; r < 8; r++) {
            float b0 = __shfl(u0[r], i2, 4);
            float b1v = __shfl(u1[r], i2, 4);
            int row = 8 * i2 + r;
            const float4 g00 = *(const float4*)(s_gw + row * (HH * DD) + 8 * l);
            const float4 g01 = *(const float4*)(s_gw + row * (HH * DD) + 8 * l + 4);
            const float4 g10 = *(const float4*)(s_gw + row * (HH * DD) + DD + 8 * l);
            const float4 g11 = *(const float4*)(s_gw + row * (HH * DD) + DD + 8 * l + 4);
            o[0] += b0 * g00.x + b1v * g10.x;
            o[1] += b0 * g00.y + b1v * g10.y;
            o[2] += b0 * g00.z + b1v * g10.z;
            o[3] += b0 * g00.w + b1v * g10.w;
            o[4] += b0 * g01.x + b1v * g11.x;
            o[5] += b0 * g01.y + b1v * g11.y;
            o[6] += b0 * g01.z + b1v * g11.z;
            o[7] += b0 * g01.w + b1v * g11.w;
        }
    }
#pragma unroll
    for (int f = 0; f < 8; f++) o[f] = fmaxf(0.5f * o[f] + s_bias[8 * l + f], 0.f);
    // fused mlp-pre: Ps (rows 0..31 of w1, +b1), Pd (rows 32..63)
    float ps[8], pd[8];
#pragma unroll
    for (int f = 0; f < 8; f++) {
        ps[f] = s_b1[8 * l + f];
        pd[f] = 0.f;
    }
#pragma unroll
    for (int i2 = 0; i2 < 4; i2++) {
#pragma unroll
        for (int r = 0; r < 8; r++) {
            float bo = __shfl(o[r], i2, 4);
            int row = 8 * i2 + r;
            const float4 wa0 = *(const float4*)(s_w1 + row * DD + 8 * l);
            const float4 wa1 = *(const float4*)(s_w1 + row * DD + 8 * l + 4);
            const float4 wb0 = *(const float4*)(s_w1 + (DD + row) * DD + 8 * l);
            const float4 wb1 = *(const float4*)(s_w1 + (DD + row) * DD + 8 * l + 4);
            ps[0] += bo * wa0.x;
            ps[1] += bo * wa0.y;
            ps[2] += bo * wa0.z;
            ps[3] += bo * wa0.w;
            ps[4] += bo * wa1.x;
            ps[5] += bo * wa1.y;
            ps[6] += bo * wa1.z;
            ps[7] += bo * wa1.w;
            pd[0] += bo * wb0.x;
            pd[1] += bo * wb0.y;
            pd[2] += bo * wb0.z;
            pd[3] += bo * wb0.w;
            pd[4] += bo * wb1.x;
            pd[5] += bo * wb1.y;
            pd[6] += bo * wb1.z;
            pd[7] += bo * wb1.w;
        }
    }
    uint4 pw;
    *reinterpret_cast<__half2*>(&pw.x) = __floats2half2_rn(ps[0], ps[1]);
    *reinterpret_cast<__half2*>(&pw.y) = __floats2half2_rn(ps[2], ps[3]);
    *reinterpret_cast<__half2*>(&pw.z) = __floats2half2_rn(ps[4], ps[5]);
    *reinterpret_cast<__half2*>(&pw.w) = __floats2half2_rn(ps[6], ps[7]);
    *(uint4*)((char*)Ps + (size_t)n * 64 + l * 16) = pw;
    *reinterpret_cast<__half2*>(&pw.x) = __floats2half2_rn(pd[0], pd[1]);
    *reinterpret_cast<__half2*>(&pw.y) = __floats2half2_rn(pd[2], pd[3]);
    *reinterpret_cast<__half2*>(&pw.z) = __floats2half2_rn(pd[4], pd[5]);
    *reinterpret_cast<__half2*>(&pw.w) = __floats2half2_rn(pd[6], pd[7]);
    *(uint4*)((char*)Pd + (size_t)n * 64 + l * 16) = pw;
}

// ---- Edge MLP v6: weights via wave-uniform GLOBAL reads (s_load / scalar
// cache; zero LDS). Natural load order. one thread per edge. ----
__device__ __forceinline__ void add_half_row(const __half* __restrict__ row, float acc[DD]) {
    const uint4* r4 = (const uint4*)row;
#pragma unroll
    for (int c = 0; c < 4; c++) {
        uint4 u = r4[c];
        unsigned uu[4] = {u.x, u.y, u.z, u.w};
#pragma unroll
        for (int t = 0; t < 4; t++) {
            __half2 h2 = *reinterpret_cast<const __half2*>(&uu[t]);
            float2 f = __half22float2(h2);
            acc[c * 8 + t * 2 + 0] += f.x;
            acc[c * 8 + t * 2 + 1] += f.y;
        }
    }
}

__global__ void edge_mlp_v6(const __half* __restrict__ Ps, const __half* __restrict__ Pd,
                            const float* __restrict__ eattr, const int* __restrict__ src,
                            const int* __restrict__ dst, const float* __restrict__ w1e,
                            const float* __restrict__ w2, const float* __restrict__ b2,
                            float* __restrict__ out, int E) {
    int e = blockIdx.x * blockDim.x + threadIdx.x;
    if (e >= E) return;
    float b2v = b2[0];
    int s = src[e], d = dst[e];
    float acc[DD] = {};
    add_half_row(Ps + (size_t)s * DD, acc);
    add_half_row(Pd + (size_t)d * DD, acc);
    const float4* ea4 = (const float4*)(eattr + (size_t)e * EFF);
#pragma unroll
    for (int c = 0; c < 4; c++) {
        float4 v = ea4[c];
        const float va[4] = {v.x, v.y, v.z, v.w};
#pragma unroll
        for (int r = 0; r < 4; r++) {
            // wave-uniform address: compiler scalarizes to s_load (sK$)
#pragma unroll
            for (int j4 = 0; j4 < 8; j4++) {
                const float4 w = *(const float4*)(w1e + (c * 4 + r) * DD + j4 * 4);
                acc[j4 * 4 + 0] += va[r] * w.x;
                acc[j4 * 4 + 1] += va[r] * w.y;
                acc[j4 * 4 + 2] += va[r] * w.z;
                acc[j4 * 4 + 3] += va[r] * w.w;
            }
        }
    }
    float p = b2v;
#pragma unroll
    for (int j = 0; j < DD; j++) p += fmaxf(acc[j], 0.f) * w2[j];
    out[e] = p;
}

extern "C" void kernel_launch(void* const* d_in, const int* in_sizes, int n_in,
                              void* d_out, int out_size, void* d_ws, size_t ws_size,
                              hipStream_t stream) {
    const int E = in_sizes[0] / 2;
    const int N = in_sizes[2] / DD;

    const int* src = (const int*)d_in[0];
    const int* dst = src + E;
    const float* edge_attr = (const float*)d_in[1];
    const float* node_emb = (const float*)d_in[2];
    const float* sage1_wl = (const float*)d_in[3];
    const float* sage1_bl = (const float*)d_in[4];
    const float* sage1_wr = (const float*)d_in[5];
    const float* sage2_wl = (const float*)d_in[6];
    const float* sage2_bl = (const float*)d_in[7];
    const float* sage2_wr = (const float*)d_in[8];
    const float* gat_w = (const float*)d_in[9];
    const float* gat_att_src = (const float*)d_in[10];
    const float* gat_att_dst = (const float*)d_in[11];
    const float* gat_bias = (const float*)d_in[12];
    const float* mlp_w1 = (const float*)d_in[13];
    const float* mlp_b1 = (const float*)d_in[14];
    const float* mlp_w2 = (const float*)d_in[15];
    const float* mlp_b2 = (const float*)d_in[16];
    float* out = (float*)d_out;

    const int NBINS = (N + 255) >> BIN_SHIFT;
    const int NBLK = (E + EB - 1) / EB;
    const int M = NBINS * NBLK;

    // Workspace layout (256B-aligned chunks)
    char* ws = (char*)d_ws;
    size_t off = 0;
    auto alloc = [&](size_t bytes) {
        char* p = ws + off;
        off = (off + bytes + 255) & ~(size_t)255;
        return p;
    };
    int* rowptr = (int*)alloc((size_t)(N + 1) * 4);
    int* blockSums = (int*)alloc(256 * 4);
    int* dTot = (int*)alloc(4);
    int* soff = (int*)alloc((size_t)E * 4);
    __half* x0h = (__half*)alloc((size_t)N * DD * 2);
    __half* x1h = (__half*)alloc((size_t)N * DD * 2);
    __half* x2h = (__half*)alloc((size_t)N * DD * 2);
    float2* a_s = (float2*)alloc((size_t)N * 8);
    float2* a_d = (float2*)alloc((size_t)N * 8);
    float4* c4 = (float4*)alloc(DD * 16);
    __half* Ps = (__half*)alloc((size_t)N * DD * 2);
    __half* Pd = (__half*)alloc((size_t)N * DD * 2);
    int* histA = (int*)alloc((size_t)M * 4);
    int* histScan = (int*)alloc((size_t)M * 4);
    int* pairs = (int*)alloc((size_t)E * 4);

    const int BS = 256;
    const int gE = (E + BS - 1) / BS;
    const int gN32 = (N * 32 + BS - 1) / BS;
    const int gN4 = (N * 4 + BS - 1) / BS;
    const int NBm = (M + 1023) / 1024;

    // ---- CSR build: counting sort; rowptr built inside radixC ----
    radixA_k<<<NBLK, PB_T, 0, stream>>>(dst, histA, E, NBLK, NBINS);
    scan1_k<<<NBm, 256, 0, stream>>>(histA, histScan, blockSums, M);
    scan2_k<<<1, 256, 0, stream>>>(blockSums, dTot, NBm);
    scan3_k<<<(M + BS - 1) / BS, BS, 0, stream>>>(histScan, blockSums, M);
    radixB_k<<<NBLK, PB_T, 0, stream>>>(src, dst, histScan, pairs, E, NBLK, NBINS);
    radixC_v3<<<NBINS, 256, 0, stream>>>(histScan, pairs, rowptr, soff, N, NBLK, NBINS, E);

    // ---- fp16 input conversion + attention coefficient vectors ----
    cvt_k<<<gN32, BS, 0, stream>>>(node_emb, x0h, N * DD);
    prep_c_k<<<1, 64, 0, stream>>>(gat_w, gat_att_src, gat_att_dst, c4);

    // ---- SAGE layers (layer 2 also emits GAT scores) ----
    sage4x16_k<<<gN4, BS, 0, stream>>>(x0h, rowptr, soff, sage1_wl, sage1_bl, sage1_wr,
                                       x1h, nullptr, nullptr, nullptr, N);
    sage4x16_k<<<gN4, BS, 0, stream>>>(x1h, rowptr, soff, sage2_wl, sage2_bl, sage2_wr,
                                       x2h, c4, a_s, a_d, N);

    // ---- GAT aggregate (+ inline softmax weights + fused mlp-pre) ----
    gat_agg_v11<<<gN4, BS, 0, stream>>>(x2h, a_s, a_d, rowptr, soff, gat_w, gat_bias,
                                        mlp_w1, mlp_b1, Ps, Pd, N);

    // ---- Edge MLP (weights via scalar cache, no LDS) ----
    edge_mlp_v6<<<gE, BS, 0, stream>>>(Ps, Pd, edge_attr, src, dst,
                                       mlp_w1 + 2 * DD * DD, mlp_w2, mlp_b2, out, E);
}